// Round 15
// baseline (205.296 us; speedup 1.0000x reference)
//
#include <hip/hip_runtime.h>
#include <hip/hip_bf16.h>

typedef __attribute__((ext_vector_type(4))) float f32x4;
typedef __attribute__((ext_vector_type(8))) short s16x8;
typedef __attribute__((ext_vector_type(4))) short s16x4;

#define AS1 __attribute__((address_space(1)))
#define AS3 __attribute__((address_space(3)))

__device__ __forceinline__ short f2bf(float f) {
    union { float f; unsigned u; } a; a.f = f;
    unsigned r = a.u + 0x7fff + ((a.u >> 16) & 1);
    return (short)(r >> 16);
}

__device__ __forceinline__ unsigned pk_bf16(float a, float b) {
    unsigned r;
    asm("v_cvt_pk_bf16_f32 %0, %1, %2" : "=v"(r) : "v"(a), "v"(b));
    return r;
}

// ---------------- conversion kernels ----------------

__global__ __launch_bounds__(256) void convert_f32_bf16(const float* __restrict__ in,
                                                        short* __restrict__ out, int n4) {
    int i = blockIdx.x * 256 + threadIdx.x;
    if (i < n4) {
        f32x4 v = *(const f32x4*)(in + (long)i * 4);
        s16x4 o;
        o.x = f2bf(v.x); o.y = f2bf(v.y); o.z = f2bf(v.z); o.w = f2bf(v.w);
        *(s16x4*)(out + (long)i * 4) = o;
    }
}

// src [K][N] f32 -> dst [N][K] bf16
__global__ __launch_bounds__(256) void transpose_w(const float* __restrict__ src,
                                                   short* __restrict__ dst, int K, int N) {
    __shared__ short t[64][65];
    int k0 = blockIdx.x * 64, n0 = blockIdx.y * 64;
    int tid = threadIdx.x;
    for (int i = tid; i < 64 * 64; i += 256) {
        int r = i >> 6, c = i & 63;
        t[r][c] = f2bf(src[(long)(k0 + r) * N + n0 + c]);
    }
    __syncthreads();
    for (int i = tid; i < 64 * 64; i += 256) {
        int r = i >> 6, c = i & 63;
        dst[(long)(n0 + r) * K + k0 + c] = t[c][r];
    }
}

// ---------------- GEMM v8: 256^2 tile, 8 waves, BK=64, 4-phase/K-tile counted-vmcnt ----------
// 8-phase template (guide §5): wave tile 64x128 (WARPS_M=4, WARPS_N=2), 16 MFMA/phase,
// 1 half-tile stage/phase (2 global_load_lds), vmcnt(6) once per K-tile (3 halves in flight),
// raw s_barriers (no vmcnt-0 drains in steady state), superrow XOR swizzle (verified).
// LDS 128 KB dynamic: lA[2][16384], lB[2][16384] shorts.
// Schedule per group j (buf b=j&1): P1 rd A(8)+Bn01(4), stg B-h1(j+1)->buf^1;
// P2 rd Bn23(4), stg A-h0(j+2)->buf; P3 rd Bn45+67(8), stg A-h1(j+2)->buf;
// P4 stg B-h0(j+2)->buf, vmcnt(6). Regions die >=1 barrier before overwrite (audited).

template <int MODE>
__global__ __launch_bounds__(512, 2) void gemm8(const short* __restrict__ A,
                                                const short* __restrict__ BT,
                                                const float* __restrict__ bias,
                                                float* __restrict__ outF,
                                                short* __restrict__ q_,
                                                short* __restrict__ k_,
                                                short* __restrict__ v_,
                                                int M, int N, int K) {
    extern __shared__ short smem[];
    short* lA = smem;             // [2][16384] shorts (32KB per buf)
    short* lB = smem + 32768;     // [2][16384]

    int tid = threadIdx.x;
    int lane = tid & 63, wid = tid >> 6;
    int wm = wid >> 1, wn = wid & 1;
    int lo = lane & 15, hi = lane >> 4;
    int srlo = lo >> 1, rpar = (lo & 1) << 2;

    // XCD-grouped bijective block swizzle (gridDim.x % 8 == 0)
    int bid = blockIdx.x;
    int swz = (bid & 7) * ((int)gridDim.x >> 3) + (bid >> 3);
    int NX = N >> 8;
    int bx = swz % NX, by = swz / NX;
    int m0 = by * 256, n0 = bx * 256;

    const short* Ag = A + (long)m0 * K;
    const short* Bg = BT + (long)n0 * K;

    f32x4 acc[4][8];
#pragma unroll
    for (int i = 0; i < 4; ++i)
#pragma unroll
        for (int j = 0; j < 8; ++j) acc[i][j] = (f32x4){0.f, 0.f, 0.f, 0.f};

    // staging lane constants (superrow swizzle, pre-swizzled source)
    int srl_ = tid >> 3;            // superrow-local 0..63 (covers 128 rows)
    int s_ = tid & 7;               // slot
    int cc_ = s_ ^ (srl_ & 7);      // inverse-swizzled chunk code
    int gp_ = cc_ >> 2;             // row parity
    int gk_ = (cc_ & 3) * 8;        // k offset (shorts) within 32-chunk

#define STG(Xg_, Xl_, t_, h_)                                                               \
    do {                                                                                    \
        int srg_ = (h_) * 64 + srl_;                                                        \
        long grow_ = (long)(srg_ * 2 + gp_);                                                \
        const short* s0_ = (Xg_) + grow_ * K + (t_) * 64 + gk_;                             \
        __builtin_amdgcn_global_load_lds((const AS1 void*)s0_,                              \
                                         (AS3 void*)((Xl_) + srg_ * 64 + s_ * 8), 16, 0, 0);\
        __builtin_amdgcn_global_load_lds((const AS1 void*)(s0_ + 32),                       \
                                         (AS3 void*)((Xl_) + 8192 + srg_ * 64 + s_ * 8),    \
                                         16, 0, 0);                                         \
    } while (0)

    int T = K >> 6;   // BK=64 K-tiles (12 for K=768)

    // prologue: tile0 full (4 halves), tile1 {A-h0, A-h1, B-h0}; vmcnt(6) -> tile0 landed
    STG(Ag, lA, 0, 0); STG(Ag, lA, 0, 1);
    STG(Bg, lB, 0, 0); STG(Bg, lB, 0, 1);
    if (T > 1) {
        STG(Ag, lA + 16384, 1, 0); STG(Ag, lA + 16384, 1, 1);
        STG(Bg, lB + 16384, 1, 0);
    }
    asm volatile("s_waitcnt vmcnt(6)" ::: "memory");
    __builtin_amdgcn_s_barrier();

    int soff = ((rpar + hi) ^ srlo) * 8;

    for (int j = 0; j < T; ++j) {
        int b = j & 1;
        short* lAb = lA + b * 16384;
        short* lBb = lB + b * 16384;
        short* lAn = lA + (b ^ 1) * 16384;
        short* lBn = lB + (b ^ 1) * 16384;

        // ---- P1: read A (8) + B ni0-1 (4); stage B-h1(j+1)
        s16x8 a[4][2], b01[2][2];
#pragma unroll
        for (int mi = 0; mi < 4; ++mi)
#pragma unroll
            for (int kk = 0; kk < 2; ++kk)
                a[mi][kk] = *(const s16x8*)(lAb + (kk * 128 + wm * 32 + mi * 8 + srlo) * 64 + soff);
#pragma unroll
        for (int ni = 0; ni < 2; ++ni)
#pragma unroll
            for (int kk = 0; kk < 2; ++kk)
                b01[ni][kk] = *(const s16x8*)(lBb + (kk * 128 + wn * 64 + ni * 8 + srlo) * 64 + soff);
        if (j + 1 < T) STG(Bg, lBn, j + 1, 1);
        __builtin_amdgcn_s_barrier();
        asm volatile("s_waitcnt lgkmcnt(0)" ::: "memory");
        __builtin_amdgcn_sched_barrier(0);
        __builtin_amdgcn_s_setprio(1);
#pragma unroll
        for (int mi = 0; mi < 4; ++mi)
#pragma unroll
            for (int ni = 0; ni < 2; ++ni)
#pragma unroll
                for (int kk = 0; kk < 2; ++kk)
                    acc[mi][ni] = __builtin_amdgcn_mfma_f32_16x16x32_bf16(a[mi][kk], b01[ni][kk], acc[mi][ni], 0, 0, 0);
        __builtin_amdgcn_s_setprio(0);
        __builtin_amdgcn_s_barrier();

        // ---- P2: read B ni2-3 (4); stage A-h0(j+2)
        s16x8 b23[2][2];
#pragma unroll
        for (int ni = 0; ni < 2; ++ni)
#pragma unroll
            for (int kk = 0; kk < 2; ++kk)
                b23[ni][kk] = *(const s16x8*)(lBb + (kk * 128 + wn * 64 + (ni + 2) * 8 + srlo) * 64 + soff);
        if (j + 2 < T) STG(Ag, lAb, j + 2, 0);
        __builtin_amdgcn_s_barrier();
        asm volatile("s_waitcnt lgkmcnt(0)" ::: "memory");
        __builtin_amdgcn_sched_barrier(0);
        __builtin_amdgcn_s_setprio(1);
#pragma unroll
        for (int mi = 0; mi < 4; ++mi)
#pragma unroll
            for (int ni = 0; ni < 2; ++ni)
#pragma unroll
                for (int kk = 0; kk < 2; ++kk)
                    acc[mi][2 + ni] = __builtin_amdgcn_mfma_f32_16x16x32_bf16(a[mi][kk], b23[ni][kk], acc[mi][2 + ni], 0, 0, 0);
        __builtin_amdgcn_s_setprio(0);
        __builtin_amdgcn_s_barrier();

        // ---- P3: read B ni4-7 (8); stage A-h1(j+2)
        s16x8 b45[2][2], b67[2][2];
#pragma unroll
        for (int ni = 0; ni < 2; ++ni)
#pragma unroll
            for (int kk = 0; kk < 2; ++kk) {
                b45[ni][kk] = *(const s16x8*)(lBb + (kk * 128 + wn * 64 + (ni + 4) * 8 + srlo) * 64 + soff);
                b67[ni][kk] = *(const s16x8*)(lBb + (kk * 128 + wn * 64 + (ni + 6) * 8 + srlo) * 64 + soff);
            }
        if (j + 2 < T) STG(Ag, lAb, j + 2, 1);
        __builtin_amdgcn_s_barrier();
        asm volatile("s_waitcnt lgkmcnt(0)" ::: "memory");
        __builtin_amdgcn_sched_barrier(0);
        __builtin_amdgcn_s_setprio(1);
#pragma unroll
        for (int mi = 0; mi < 4; ++mi)
#pragma unroll
            for (int ni = 0; ni < 2; ++ni)
#pragma unroll
                for (int kk = 0; kk < 2; ++kk)
                    acc[mi][4 + ni] = __builtin_amdgcn_mfma_f32_16x16x32_bf16(a[mi][kk], b45[ni][kk], acc[mi][4 + ni], 0, 0, 0);
        __builtin_amdgcn_s_setprio(0);
        __builtin_amdgcn_s_barrier();

        // ---- P4: stage B-h0(j+2); counted vmcnt (never 0 in steady state)
        if (j + 2 < T) {
            STG(Bg, lBb, j + 2, 0);
            asm volatile("s_waitcnt vmcnt(6)" ::: "memory");
        } else if (j + 1 < T) {
            asm volatile("s_waitcnt vmcnt(0)" ::: "memory");
        }
        __builtin_amdgcn_s_barrier();
        __builtin_amdgcn_s_setprio(1);
#pragma unroll
        for (int mi = 0; mi < 4; ++mi)
#pragma unroll
            for (int ni = 0; ni < 2; ++ni)
#pragma unroll
                for (int kk = 0; kk < 2; ++kk)
                    acc[mi][6 + ni] = __builtin_amdgcn_mfma_f32_16x16x32_bf16(a[mi][kk], b67[ni][kk], acc[mi][6 + ni], 0, 0, 0);
        __builtin_amdgcn_s_setprio(0);
        __builtin_amdgcn_s_barrier();
    }
#undef STG

    // ---- epilogue
    float bs[8];
#pragma unroll
    for (int ni = 0; ni < 8; ++ni) bs[ni] = bias[n0 + wn * 128 + ni * 16 + lo];

    if (MODE == 1) {
        int bidx = m0 >> 10;
        int trow0 = (m0 & 1023) + wm * 64;
#pragma unroll
        for (int nh = 0; nh < 2; ++nh) {
            int blk = ((n0 + wn * 128) >> 6) + nh;      // 0..35, wave-uniform
            int part = (blk >= 24) ? 2 : (blk >= 12 ? 1 : 0);
            int hh = blk - part * 12;
            long gb_ = ((long)(bidx * 12 + hh)) << 16;  // *65536
            if (part == 2) {
#pragma unroll
                for (int mi = 0; mi < 4; ++mi)
#pragma unroll
                    for (int n2 = 0; n2 < 4; ++n2) {
                        int ni = nh * 4 + n2;
                        s16x4 o;
                        o.x = f2bf(acc[mi][ni][0] + bs[ni]);
                        o.y = f2bf(acc[mi][ni][1] + bs[ni]);
                        o.z = f2bf(acc[mi][ni][2] + bs[ni]);
                        o.w = f2bf(acc[mi][ni][3] + bs[ni]);
                        int tq = trow0 + mi * 16 + hi * 4;
                        *(s16x4*)(v_ + gb_ + (long)(n2 * 16 + lo) * 1024 + tq) = o;
                    }
            } else {
                short* dst = (part == 0) ? q_ : k_;
                float scl = (part == 0) ? 0.180336880f : 1.0f;  // (1/8)*log2(e) fold for q
#pragma unroll
                for (int mi = 0; mi < 4; ++mi)
#pragma unroll
                    for (int n2 = 0; n2 < 4; ++n2) {
                        int ni = nh * 4 + n2;
#pragma unroll
                        for (int r = 0; r < 4; ++r) {
                            int trow = trow0 + mi * 16 + hi * 4 + r;
                            float v = (acc[mi][ni][r] + bs[ni]) * scl;
                            dst[gb_ + (long)trow * 64 + n2 * 16 + lo] = f2bf(v);
                        }
                    }
            }
        }
    } else {
#pragma unroll
        for (int mi = 0; mi < 4; ++mi)
#pragma unroll
            for (int ni = 0; ni < 8; ++ni)
#pragma unroll
                for (int r = 0; r < 4; ++r) {
                    int gm = m0 + wm * 64 + mi * 16 + hi * 4 + r;
                    int gn = n0 + wn * 128 + ni * 16 + lo;
                    outF[(long)gm * N + gn] = acc[mi][ni][r] + bs[ni];
                }
    }
}

// ---------------- flash attention v9: 24KB LDS + defer-max (T13) ----------------

__device__ __forceinline__ void qk_softmax(const short* __restrict__ Kb_,
                                           int kv0, int qb0, bool diag,
                                           s16x8 bq0, s16x8 bq1,
                                           f32x4 (&ov)[4], float& mrun, float& lrun,
                                           s16x8 (&ap)[2],
                                           int lo, int hi, int hi2, int sA, int sB,
                                           int sl0, int sl1) {
    f32x4 s[4];
    __builtin_amdgcn_s_setprio(1);
#pragma unroll
    for (int n = 0; n < 4; ++n) {
        const short* kr = Kb_ + (n * 16 + lo) * 64;
        s16x8 kf0 = *(const s16x8*)(kr + sl0);
        s16x8 kf1 = *(const s16x8*)(kr + sl1);
        f32x4 t = (f32x4){0.f, 0.f, 0.f, 0.f};
        t = __builtin_amdgcn_mfma_f32_16x16x32_bf16(kf0, bq0, t, 0, 0, 0);
        t = __builtin_amdgcn_mfma_f32_16x16x32_bf16(kf1, bq1, t, 0, 0, 0);
        s[n] = t;
    }
    __builtin_amdgcn_s_setprio(0);

    int qglob = qb0 + lo;
    if (diag) {
#pragma unroll
        for (int n = 0; n < 4; ++n)
#pragma unroll
            for (int r = 0; r < 4; ++r)
                if (kv0 + n * 16 + hi * 4 + r > qglob) s[n][r] = -3.0e38f;
    }
    float mx = fmaxf(fmaxf(fmaxf(s[0][0], s[0][1]), fmaxf(s[0][2], s[0][3])),
                     fmaxf(fmaxf(s[1][0], s[1][1]), fmaxf(s[1][2], s[1][3])));
    mx = fmaxf(mx, fmaxf(fmaxf(fmaxf(s[2][0], s[2][1]), fmaxf(s[2][2], s[2][3])),
                         fmaxf(fmaxf(s[3][0], s[3][1]), fmaxf(s[3][2], s[3][3]))));
    mx = fmaxf(mx, __shfl_xor(mx, 16));
    mx = fmaxf(mx, __shfl_xor(mx, 32));
    if (!__all(mx - mrun <= 8.0f)) {
        float mn = fmaxf(mrun, mx);
        float alpha = exp2f(mrun - mn);
        mrun = mn;
        lrun *= alpha;
#pragma unroll
        for (int nd = 0; nd < 4; ++nd)
#pragma unroll
            for (int r = 0; r < 4; ++r) ov[nd][r] *= alpha;
    }
    float m = mrun;
    float rs = 0.f;
#pragma unroll
    for (int n = 0; n < 4; ++n)
#pragma unroll
        for (int r = 0; r < 4; ++r) {
            float p = exp2f(s[n][r] - m);
            s[n][r] = p;
            rs += p;
        }
    rs += __shfl_xor(rs, 16);
    rs += __shfl_xor(rs, 32);
    lrun += rs;

    unsigned W[4][2];
#pragma unroll
    for (int n = 0; n < 4; ++n) {
        W[n][0] = pk_bf16(s[n][0], s[n][1]);
        W[n][1] = pk_bf16(s[n][2], s[n][3]);
    }
#pragma unroll
    for (int kc = 0; kc < 2; ++kc) {
        unsigned a0 = __shfl(W[kc * 2][0], sA), b0 = __shfl(W[kc * 2 + 1][0], sA);
        unsigned a1 = __shfl(W[kc * 2][1], sA), b1 = __shfl(W[kc * 2 + 1][1], sA);
        unsigned a2 = __shfl(W[kc * 2][0], sB), b2 = __shfl(W[kc * 2 + 1][0], sB);
        unsigned a3 = __shfl(W[kc * 2][1], sB), b3 = __shfl(W[kc * 2 + 1][1], sB);
        union { unsigned u[4]; s16x8 v; } cv;
        cv.u[0] = hi2 ? b0 : a0;
        cv.u[1] = hi2 ? b1 : a1;
        cv.u[2] = hi2 ? b2 : a2;
        cv.u[3] = hi2 ? b3 : a3;
        ap[kc] = cv.v;
    }
}

__device__ __forceinline__ void pv_accum(const short* __restrict__ Vb_,
                                         const s16x8 (&ap)[2], f32x4 (&ov)[4],
                                         int lo, int sl0, int sl1) {
    __builtin_amdgcn_s_setprio(1);
#pragma unroll
    for (int nd = 0; nd < 4; ++nd) {
        const short* vr = Vb_ + (nd * 16 + lo) * 64;
        s16x8 av0 = *(const s16x8*)(vr + sl0);
        s16x8 av1 = *(const s16x8*)(vr + sl1);
        ov[nd] = __builtin_amdgcn_mfma_f32_16x16x32_bf16(av0, ap[0], ov[nd], 0, 0, 0);
        ov[nd] = __builtin_amdgcn_mfma_f32_16x16x32_bf16(av1, ap[1], ov[nd], 0, 0, 0);
    }
    __builtin_amdgcn_s_setprio(0);
}

__device__ __forceinline__ void store_out(const f32x4 (&ov)[4], float lrun,
                                          long rowbase, int qb0, int h,
                                          int lo, int hi, short* __restrict__ y) {
    float inv = 1.0f / lrun;
    long row = (rowbase + qb0 + lo) * 768 + h * 64;
#pragma unroll
    for (int nd = 0; nd < 4; ++nd)
#pragma unroll
        for (int j2 = 0; j2 < 2; ++j2) {
            unsigned pv = pk_bf16(ov[nd][2 * j2] * inv, ov[nd][2 * j2 + 1] * inv);
            *(unsigned*)(y + row + nd * 16 + hi * 4 + 2 * j2) = pv;
        }
}

// grid 1536; block = 4 waves sharing (b,h); paired q-fragments (qp, 15-qp) -> 17 tiles.
__global__ __launch_bounds__(256) void flash_attn9(const short* __restrict__ qpk,
                                                   const short* __restrict__ kpk,
                                                   const short* __restrict__ vtg,
                                                   short* __restrict__ y) {
    __shared__ short Kb[2][4096];
    __shared__ short Vb[4096];

    int d = blockIdx.x;
    int qp = d / 192, g = d % 192;
    int h = g % 12, b = g / 12;
    int tid = threadIdx.x, lane = tid & 63, w = tid >> 6;
    int lo = lane & 15, hi = lane >> 4, hi2 = hi >> 1;
    long rowbase = (long)b * 1024;
    const short* kb_g = kpk + (long)g * 65536;
    const short* vt_g = vtg + (long)g * 65536;
    int sA = ((hi & 1) * 2) * 16 + lo, sB = sA + 16;

    int rl = lane >> 3;
    int cs8 = (((lane & 7) ^ rl)) * 8;
    int r0 = w * 8 + rl;
    int sl0 = (hi ^ (lo & 7)) * 8;
    int sl1 = ((hi + 4) ^ (lo & 7)) * 8;

    int qbA = qp * 64 + w * 16;
    int qbB = (15 - qp) * 64 + w * 16;

    f32x4 ov[4];
    float mrun = -3.0e38f, lrun = 0.f;
#pragma unroll
    for (int nd = 0; nd < 4; ++nd) ov[nd] = (f32x4){0.f, 0.f, 0.f, 0.f};
    s16x8 bq0, bq1;
    {
        const short* qrow = qpk + ((long)g * 1024 + qbA + lo) * 64;
        bq0 = *(const s16x8*)(qrow + hi * 8);
        bq1 = *(const s16x8*)(qrow + 32 + hi * 8);
    }

#define STAGE_K(kv0_, buf_)                                                                  \
    do {                                                                                     \
        _Pragma("unroll")                                                                    \
        for (int i_ = 0; i_ < 2; ++i_) {                                                     \
            int r_ = i_ * 32 + r0;                                                           \
            __builtin_amdgcn_global_load_lds(                                                \
                (const AS1 void*)(kb_g + (long)((kv0_) + r_) * 64 + cs8),                    \
                (AS3 void*)(Kb[buf_] + (i_ * 32 + w * 8) * 64), 16, 0, 0);                   \
        }                                                                                    \
    } while (0)

#define STAGE_V(kv0_)                                                                        \
    do {                                                                                     \
        _Pragma("unroll")                                                                    \
        for (int i_ = 0; i_ < 2; ++i_) {                                                     \
            int r_ = i_ * 32 + r0;                                                           \
            __builtin_amdgcn_global_load_lds(                                                \
                (const AS1 void*)(vt_g + (long)r_ * 1024 + (kv0_) + cs8),                    \
                (AS3 void*)(Vb + (i_ * 32 + w * 8) * 64), 16, 0, 0);                         \
        }                                                                                    \
    } while (0)

    STAGE_K(0, 0);
    STAGE_V(0);
    __syncthreads();

    int cur = 0;
    for (int u = 0; u < 17; ++u) {
        int nu = u + 1;
        int nkv0 = (nu <= qp) ? nu * 64 : (nu - qp - 1) * 64;
        if (nu < 17) STAGE_K(nkv0, cur ^ 1);

        bool phaseA = (u <= qp);
        int kv0 = phaseA ? u * 64 : (u - qp - 1) * 64;
        int qb0 = phaseA ? qbA : qbB;
        bool diag = phaseA ? (u == qp) : (u == 16);

        s16x8 ap[2];
        qk_softmax(Kb[cur], kv0, qb0, diag, bq0, bq1, ov, mrun, lrun, ap,
                   lo, hi, hi2, sA, sB, sl0, sl1);

        __syncthreads();   // A: drains all waves' K+V DMAs
        __builtin_amdgcn_sched_barrier(0);

        pv_accum(Vb, ap, ov, lo, sl0, sl1);

        if (phaseA && u == qp) {
            store_out(ov, lrun, rowbase, qbA, h, lo, hi, y);
            const short* qrow = qpk + ((long)g * 1024 + qbB + lo) * 64;
            bq0 = *(const s16x8*)(qrow + hi * 8);
            bq1 = *(const s16x8*)(qrow + 32 + hi * 8);
#pragma unroll
            for (int nd = 0; nd < 4; ++nd) ov[nd] = (f32x4){0.f, 0.f, 0.f, 0.f};
            mrun = -3.0e38f; lrun = 0.f;
        }

        __builtin_amdgcn_s_barrier();   // B: all waves done reading Vb
        __builtin_amdgcn_sched_barrier(0);
        if (nu < 17) STAGE_V(nkv0);
        cur ^= 1;
    }
    store_out(ov, lrun, rowbase, qbB, h, lo, hi, y);
#undef STAGE_K
#undef STAGE_V
}

// ---------------- launch ----------------

extern "C" void kernel_launch(void* const* d_in, const int* in_sizes, int n_in,
                              void* d_out, int out_size, void* d_ws, size_t ws_size,
                              hipStream_t stream) {
    const float* x      = (const float*)d_in[0];
    const float* w_attn = (const float*)d_in[1];
    const float* b_attn = (const float*)d_in[2];
    const float* w_proj = (const float*)d_in[3];
    const float* b_proj = (const float*)d_in[4];

    char* ws = (char*)d_ws;
    short* x_bf = (short*)ws;                      // 25165824 B
    short* qpk  = (short*)(ws + 25165824);         // q packed [g][1024][64]
    short* kpk  = (short*)(ws + 50331648);         // k packed [g][1024][64]
    short* vt   = (short*)(ws + 75497472);         // V^T [g][64][1024] (direct)
    short* yb   = (short*)(ws + 100663296);
    short* waT  = (short*)(ws + 125829120);
    short* wpT  = (short*)(ws + 129368064);

    // allow 128KB dynamic LDS for the 8-phase GEMMs (host-side attr, graph-capture safe)
    hipFuncSetAttribute(reinterpret_cast<const void*>(&gemm8<1>),
                        hipFuncAttributeMaxDynamicSharedMemorySize, 131072);
    hipFuncSetAttribute(reinterpret_cast<const void*>(&gemm8<0>),
                        hipFuncAttributeMaxDynamicSharedMemorySize, 131072);

    // x -> bf16
    convert_f32_bf16<<<dim3(12288), dim3(256), 0, stream>>>(x, x_bf, 3145728);
    // weight transposes (to [N][K] bf16)
    transpose_w<<<dim3(12, 36), dim3(256), 0, stream>>>(w_attn, waT, 768, 2304);
    transpose_w<<<dim3(12, 12), dim3(256), 0, stream>>>(w_proj, wpT, 768, 768);
    // QKV projection (+bias); q/k packed, V written directly transposed. 64x9=576 blocks.
    gemm8<1><<<dim3(576), dim3(512), 131072, stream>>>(x_bf, waT, b_attn,
                                                       (float*)nullptr, qpk, kpk, vt,
                                                       16384, 2304, 768);
    // causal flash attention (24KB LDS, defer-max)
    flash_attn9<<<dim3(1536), dim3(256), 0, stream>>>(qpk, kpk, vt, yb);
    // output projection -> fp32. 64x3=192 blocks.
    gemm8<0><<<dim3(192), dim3(512), 131072, stream>>>(yb, wpT, b_proj,
                                                       (float*)d_out, (short*)nullptr,
                                                       (short*)nullptr, (short*)nullptr,
                                                       16384, 768, 768);
}